// Round 1
// baseline (101.897 us; speedup 1.0000x reference)
//
#include <hip/hip_runtime.h>

#define B_ 16
#define M_ 200
#define S_ 32
#define C_ 2048
#define V_ 32000
#define D_ 128
#define HOPS_ 3

// Kernel 1: embedding-bag sums.
// blocks [0, B*M): m[b,i,d] = sum_s embed_A[stories[b,i,s], d]
// blocks [B*M, B*M+B): u[b,d] = sum_s embed_A[query[b,s], d]
__global__ void k_embed(const int* __restrict__ stories, const int* __restrict__ query,
                        const float* __restrict__ embA,
                        float* __restrict__ m, float* __restrict__ u) {
    int blk = blockIdx.x;
    int d = threadIdx.x;                 // 128 threads, one per D column
    const int* idx;
    float* dst;
    if (blk < B_ * M_) { idx = stories + blk * S_; dst = m + blk * D_; }
    else { int b = blk - B_ * M_; idx = query + b * S_; dst = u + b * D_; }
    float acc = 0.f;
#pragma unroll
    for (int s = 0; s < S_; ++s) acc += embA[idx[s] * D_ + d];
    dst[d] = acc;
}

// Kernel 2: 3 memory hops. One block (256 threads) per batch.
__global__ void k_hops(const float* __restrict__ m, const float* __restrict__ Hw,
                       const float* __restrict__ Hb, float* __restrict__ u) {
    int b = blockIdx.x;
    int t = threadIdx.x;
    __shared__ float su[D_];
    __shared__ float sattn[M_];
    __shared__ float smx, ssum;
    if (t < D_) su[t] = u[b * D_ + t];
    __syncthreads();
    for (int hop = 0; hop < HOPS_; ++hop) {
        // scores: attn[i] = m[b,i,:] . u
        for (int i = t; i < M_; i += 256) {
            const float4* mr = (const float4*)(m + (b * M_ + i) * D_);
            const float4* uu = (const float4*)su;
            float dot = 0.f;
#pragma unroll
            for (int j = 0; j < D_ / 4; ++j) {
                float4 a = mr[j]; float4 x = uu[j];
                dot += a.x * x.x + a.y * x.y + a.z * x.z + a.w * x.w;
            }
            sattn[i] = dot;
        }
        __syncthreads();
        // softmax reduce by wave 0
        if (t < 64) {
            float mx = -3.0e38f;
            for (int i = t; i < M_; i += 64) mx = fmaxf(mx, sattn[i]);
#pragma unroll
            for (int o = 32; o; o >>= 1) mx = fmaxf(mx, __shfl_xor(mx, o));
            float sm = 0.f;
            for (int i = t; i < M_; i += 64) sm += expf(sattn[i] - mx);
#pragma unroll
            for (int o = 32; o; o >>= 1) sm += __shfl_xor(sm, o);
            if (t == 0) { smx = mx; ssum = sm; }
        }
        __syncthreads();
        float mxv = smx, inv = 1.f / ssum;
        for (int i = t; i < M_; i += 256) sattn[i] = expf(sattn[i] - mxv) * inv;
        __syncthreads();
        // o[d] = sum_i attn[i]*m[b,i,d];  u_new = Hw @ u + Hb + o
        float un = 0.f;
        if (t < D_) {
            float o = 0.f;
            for (int i = 0; i < M_; ++i) o += sattn[i] * m[(b * M_ + i) * D_ + t];
            un = Hb[t] + o;
            for (int k = 0; k < D_; ++k) un += Hw[t * D_ + k] * su[k];
        }
        __syncthreads();
        if (t < D_) su[t] = un;
        __syncthreads();
    }
    if (t < D_) u[b * D_ + t] = su[t];
}

// Kernel 3: P[v,b] = dot(u[b,:], embed_W[v,:])   (layout [V][B] for coalesced cand lookups)
__global__ void k_pv(const float* __restrict__ u, const float* __restrict__ embW,
                     float* __restrict__ P) {
    int g = blockIdx.x * 256 + threadIdx.x;   // g = v*16 + b
    int b = g & (B_ - 1);
    int v = g >> 4;
    const float4* w  = (const float4*)(embW + v * D_);
    const float4* uu = (const float4*)(u + b * D_);
    float acc = 0.f;
#pragma unroll 8
    for (int j = 0; j < D_ / 4; ++j) {
        float4 a = w[j]; float4 x = uu[j];
        acc += a.x * x.x + a.y * x.y + a.z * x.z + a.w * x.w;
    }
    P[v * B_ + b] = acc;
}

// Kernel 4: logits[b,c] = sum_s P[cand[c,s],b] + sum_s P[E[b,c,s],b]
__global__ void k_logits(const int* __restrict__ cand, const int* __restrict__ E,
                         const float* __restrict__ P, float* __restrict__ out) {
    int g = blockIdx.x * 256 + threadIdx.x;   // g = b*C + c
    int c = g & (C_ - 1);
    int b = g >> 11;
    const int4* cs = (const int4*)(cand + c * S_);
    const int4* es = (const int4*)(E + g * S_);   // (b*C+c)*S == g*S
    float acc = 0.f;
#pragma unroll
    for (int j = 0; j < S_ / 4; ++j) {
        int4 wv = cs[j];
        acc += P[wv.x * B_ + b] + P[wv.y * B_ + b] + P[wv.z * B_ + b] + P[wv.w * B_ + b];
        int4 ev = es[j];
        acc += P[ev.x * B_ + b] + P[ev.y * B_ + b] + P[ev.z * B_ + b] + P[ev.w * B_ + b];
    }
    out[g] = acc;
}

extern "C" void kernel_launch(void* const* d_in, const int* in_sizes, int n_in,
                              void* d_out, int out_size, void* d_ws, size_t ws_size,
                              hipStream_t stream) {
    const int*   stories = (const int*)d_in[0];
    const int*   query   = (const int*)d_in[1];
    const int*   E       = (const int*)d_in[2];
    const int*   cand    = (const int*)d_in[3];
    const float* embA    = (const float*)d_in[4];
    const float* embW    = (const float*)d_in[5];
    const float* Hw      = (const float*)d_in[6];
    const float* Hb      = (const float*)d_in[7];
    float* out = (float*)d_out;

    char* ws = (char*)d_ws;
    float* u = (float*)ws;                                    // B*D      =   8 KB
    float* m = (float*)(ws + 8192);                           // B*M*D f32 = 1.6 MB
    float* P = (float*)(ws + 8192 + (size_t)B_ * M_ * D_ * 4); // V*B f32  = 2.0 MB

    hipLaunchKernelGGL(k_embed,  dim3(B_ * M_ + B_), dim3(D_), 0, stream,
                       stories, query, embA, m, u);
    hipLaunchKernelGGL(k_hops,   dim3(B_), dim3(256), 0, stream, m, Hw, Hb, u);
    hipLaunchKernelGGL(k_pv,     dim3((B_ * V_) / 256), dim3(256), 0, stream, u, embW, P);
    hipLaunchKernelGGL(k_logits, dim3((B_ * C_) / 256), dim3(256), 0, stream, cand, E, P, out);
}

// Round 2
// 91.778 us; speedup vs baseline: 1.1103x; 1.1103x over previous
//
#include <hip/hip_runtime.h>

#define B_ 16
#define M_ 200
#define S_ 32
#define C_ 2048
#define V_ 32000
#define D_ 128
#define HOPS_ 3

// Kernel 1: embedding-bag sums, float4-vectorized (16 B/lane).
// 32 lanes per sentence, 8 sentences per 256-thread block.
// sentences [0, B*M): m[b,i,d] = sum_s embed_A[stories[b,i,s], d]
// sentences [B*M, B*M+B): u[b,d] = sum_s embed_A[query[b,s], d]
__global__ void k_embed(const int* __restrict__ stories, const int* __restrict__ query,
                        const float* __restrict__ embA,
                        float* __restrict__ m, float* __restrict__ u) {
    int lane = threadIdx.x & 31;
    int sent = (blockIdx.x * 256 + threadIdx.x) >> 5;
    if (sent >= B_ * M_ + B_) return;
    const int* idx;
    float* dst;
    if (sent < B_ * M_) { idx = stories + sent * S_; dst = m + sent * D_; }
    else { int b = sent - B_ * M_; idx = query + b * S_; dst = u + b * D_; }
    float4 acc = {0.f, 0.f, 0.f, 0.f};
#pragma unroll
    for (int s = 0; s < S_; ++s) {
        const float4* row = (const float4*)(embA + (size_t)idx[s] * D_);
        float4 a = row[lane];
        acc.x += a.x; acc.y += a.y; acc.z += a.z; acc.w += a.w;
    }
    ((float4*)dst)[lane] = acc;
}

// Kernel 2: 3 memory hops. One block of 1024 threads (16 waves) per batch.
// All global m reads are coalesced row-major; reductions via shfl + small LDS.
__global__ void __launch_bounds__(1024) k_hops(
        const float* __restrict__ m, const float* __restrict__ Hw,
        const float* __restrict__ Hb, float* __restrict__ u) {
    int b = blockIdx.x;
    int t = threadIdx.x;
    int lane = t & 63;
    int wave = t >> 6;            // 16 waves
    __shared__ float su[D_];
    __shared__ float sattn[M_];
    __shared__ float sred[16 * D_];   // per-wave o partials [16][128]
    __shared__ float smx, ssum;
    const float* mb = m + (size_t)b * M_ * D_;
    if (t < D_) su[t] = u[b * D_ + t];
    __syncthreads();

    for (int hop = 0; hop < HOPS_; ++hop) {
        // ---- scores: attn[i] = m[b,i,:] . u   (one row per wave, shfl reduce)
        float2 uu = ((const float2*)su)[lane];     // d = 2*lane, 2*lane+1
        for (int i = wave; i < M_; i += 16) {
            float2 mv = ((const float2*)(mb + i * D_))[lane];
            float p = mv.x * uu.x + mv.y * uu.y;
#pragma unroll
            for (int o = 32; o; o >>= 1) p += __shfl_xor(p, o);
            if (lane == 0) sattn[i] = p;
        }
        __syncthreads();
        // ---- softmax max/sum by wave 0
        if (wave == 0) {
            float mx = -3.0e38f;
            for (int i = lane; i < M_; i += 64) mx = fmaxf(mx, sattn[i]);
#pragma unroll
            for (int o = 32; o; o >>= 1) mx = fmaxf(mx, __shfl_xor(mx, o));
            float sm = 0.f;
            for (int i = lane; i < M_; i += 64) sm += expf(sattn[i] - mx);
#pragma unroll
            for (int o = 32; o; o >>= 1) sm += __shfl_xor(sm, o);
            if (lane == 0) { smx = mx; ssum = sm; }
        }
        __syncthreads();
        if (t < M_) sattn[t] = expf(sattn[t] - smx) * (1.f / ssum);
        __syncthreads();
        // ---- o[d] = sum_i attn[i] * m[b,i,d]  (per-wave partials, coalesced rows)
        float2 oacc = {0.f, 0.f};
        for (int i = wave; i < M_; i += 16) {
            float a = sattn[i];
            float2 mv = ((const float2*)(mb + i * D_))[lane];
            oacc.x += a * mv.x; oacc.y += a * mv.y;
        }
        ((float2*)sred)[wave * 64 + lane] = oacc;   // sred[wave][d]
        __syncthreads();
        // ---- u_new[d] = Hb[d] + o[d] + sum_k Hw[d,k]*su[k]
        // 8 lanes per d: t = d*8 + k8
        int d  = t >> 3;
        int k8 = t & 7;
        float tot = sred[k8 * D_ + d] + sred[(k8 + 8) * D_ + d];
        for (int k = k8; k < D_; k += 8) tot += Hw[d * D_ + k] * su[k];
#pragma unroll
        for (int o = 1; o < 8; o <<= 1) tot += __shfl_xor(tot, o);
        float un = Hb[d] + tot;      // valid on k8==0 lanes
        __syncthreads();
        if (k8 == 0) su[d] = un;
        __syncthreads();
    }
    if (t < D_) u[b * D_ + t] = su[t];
}

// Kernel 3: P[v,b] = dot(u[b,:], embed_W[v,:])   (layout [V][B] for cand lookups)
__global__ void k_pv(const float* __restrict__ u, const float* __restrict__ embW,
                     float* __restrict__ P) {
    int g = blockIdx.x * 256 + threadIdx.x;   // g = v*16 + b
    int b = g & (B_ - 1);
    int v = g >> 4;
    const float4* w  = (const float4*)(embW + (size_t)v * D_);
    const float4* uu = (const float4*)(u + b * D_);
    float acc = 0.f;
#pragma unroll 8
    for (int j = 0; j < D_ / 4; ++j) {
        float4 a = w[j]; float4 x = uu[j];
        acc += a.x * x.x + a.y * x.y + a.z * x.z + a.w * x.w;
    }
    P[v * B_ + b] = acc;
}

// Kernel 4: logits[b,c] = sum_s P[cand[c,s],b] + sum_s P[E[b,c,s],b]
// 4 threads per (b,c), each handles an s-quarter (8 words); shfl combine.
__global__ void k_logits(const int* __restrict__ cand, const int* __restrict__ E,
                         const float* __restrict__ P, float* __restrict__ out) {
    int g4 = blockIdx.x * 256 + threadIdx.x;  // (b*C + c)*4 + q
    int q = g4 & 3;
    int g = g4 >> 2;
    int c = g & (C_ - 1);
    int b = g >> 11;
    const int4* cs = (const int4*)(cand + c * S_ + q * 8);
    const int4* es = (const int4*)(E + (size_t)g * S_ + q * 8);
    float acc = 0.f;
#pragma unroll
    for (int j = 0; j < 2; ++j) {
        int4 wv = cs[j];
        acc += P[wv.x * B_ + b] + P[wv.y * B_ + b] + P[wv.z * B_ + b] + P[wv.w * B_ + b];
        int4 ev = es[j];
        acc += P[ev.x * B_ + b] + P[ev.y * B_ + b] + P[ev.z * B_ + b] + P[ev.w * B_ + b];
    }
    acc += __shfl_xor(acc, 1);
    acc += __shfl_xor(acc, 2);
    if (q == 0) out[g] = acc;
}

extern "C" void kernel_launch(void* const* d_in, const int* in_sizes, int n_in,
                              void* d_out, int out_size, void* d_ws, size_t ws_size,
                              hipStream_t stream) {
    const int*   stories = (const int*)d_in[0];
    const int*   query   = (const int*)d_in[1];
    const int*   E       = (const int*)d_in[2];
    const int*   cand    = (const int*)d_in[3];
    const float* embA    = (const float*)d_in[4];
    const float* embW    = (const float*)d_in[5];
    const float* Hw      = (const float*)d_in[6];
    const float* Hb      = (const float*)d_in[7];
    float* out = (float*)d_out;

    char* ws = (char*)d_ws;
    float* u = (float*)ws;                                      // B*D       =   8 KB
    float* m = (float*)(ws + 8192);                             // B*M*D f32 = 1.6 MB
    float* P = (float*)(ws + 8192 + (size_t)B_ * M_ * D_ * 4);  // V*B  f32  = 2.0 MB

    hipLaunchKernelGGL(k_embed,  dim3((B_ * M_ + B_) * 32 / 256), dim3(256), 0, stream,
                       stories, query, embA, m, u);
    hipLaunchKernelGGL(k_hops,   dim3(B_), dim3(1024), 0, stream, m, Hw, Hb, u);
    hipLaunchKernelGGL(k_pv,     dim3((B_ * V_) / 256), dim3(256), 0, stream, u, embW, P);
    hipLaunchKernelGGL(k_logits, dim3((B_ * C_ * 4) / 256), dim3(256), 0, stream,
                       cand, E, P, out);
}